// Round 9
// baseline (901.483 us; speedup 1.0000x reference)
//
#include <hip/hip_runtime.h>
#include <hip/hip_bf16.h>

// B,N,D,H = 4,2048,512,8 (DK=64). fp32 I/O; bf16 intermediates in ws.
// v12 = v11 (cvt4 + proj1g + proj2p pipelined GEMMs) with attn v9:
// SWAPPED QK^T (mfma(K,Q) -> S^T) puts P in the k=16 PV A-fragment layout
// (m=row=quad*4+r, n=col=lane16) -> own-half P stays IN REGISTERS.
// Each wave PVs its 4 assigned heads x both m-halves (2x k=16 MFMA per
// d-tile): own half from regs, partner half via shrunken Px (18KB; 16
// scalar writes + 4x8B reads vs v8's 32 writes + 128B reads). Output per
// wave is complete (4 heads x 512 d) -> same partial-A store, no reduce.
// LDS bytes/thread/chunk -22%; pipeline/vmcnt ledger identical to v8.
#define B_  4
#define N_  2048
#define D_  512
#define H_  8

typedef unsigned short u16;
typedef __attribute__((ext_vector_type(8))) unsigned short ushort8;
typedef __attribute__((ext_vector_type(4))) unsigned short us4;
typedef __attribute__((ext_vector_type(8))) short short8;
typedef __attribute__((ext_vector_type(4))) short short4v;
typedef __attribute__((ext_vector_type(4))) float float4v;

__device__ __forceinline__ float bf2f(u16 u) {
    union { unsigned int i; float f; } v;
    v.i = ((unsigned int)u) << 16;
    return v.f;
}
__device__ __forceinline__ u16 f2bf(float f) {          // RNE
    union { float f; unsigned int i; } v;
    v.f = f;
    unsigned int r = v.i + 0x7FFFu + ((v.i >> 16) & 1u);
    return (u16)(r >> 16);
}
__device__ __forceinline__ u16 f2bf_fast(float f) {     // round-half-up
    union { float f; unsigned int i; } v;
    v.f = f;
    return (u16)((v.i + 0x8000u) >> 16);
}

// k=16 bf16 MFMA: builtin if present, else inline asm (ISA-verified op).
__device__ __forceinline__ float4v mfma16(short4v a, short4v b, float4v c) {
#if __has_builtin(__builtin_amdgcn_mfma_f32_16x16x16bf16_1k)
    return __builtin_amdgcn_mfma_f32_16x16x16bf16_1k(a, b, c, 0, 0, 0);
#else
    float4v d = c;
    asm volatile("v_mfma_f32_16x16x16_bf16 %0, %1, %2, %0"
                 : "+v"(d) : "v"(a), "v"(b));
    return d;
#endif
}

// async global->LDS, 16B/lane, dest = wave-uniform base + lane*16 (m104 rule)
__device__ __forceinline__ void gload_lds16(const void* g, void* l) {
    __builtin_amdgcn_global_load_lds(
        (const __attribute__((address_space(1))) unsigned int*)g,
        (__attribute__((address_space(3))) unsigned int*)l, 16, 0, 0);
}

#define WAIT_VM(N) do { \
    asm volatile("s_waitcnt vmcnt(" #N ")" ::: "memory"); \
    __builtin_amdgcn_sched_barrier(0); } while (0)
#define WAIT_LGKM0 do { \
    asm volatile("s_waitcnt lgkmcnt(0)" ::: "memory"); \
    __builtin_amdgcn_sched_barrier(0); } while (0)
#define BARRIER do { \
    __builtin_amdgcn_s_barrier(); \
    __builtin_amdgcn_sched_barrier(0); } while (0)

// ---------------------------------------------------------------------------
// wconv: Wq,Wo fp32 -> bf16, out = [Wqb | Wob]. grid (128, 2) x 256. Path B.
// ---------------------------------------------------------------------------
__global__ __launch_bounds__(256) void wconv(
    const float* __restrict__ Wq, const float* __restrict__ Wo,
    u16* __restrict__ out)
{
    const int idx = (blockIdx.x * 256 + threadIdx.x) * 8;
    const float* src = blockIdx.y ? Wo : Wq;
    u16* dst = out + (size_t)blockIdx.y * (D_ * D_) + idx;
    float4v a = *(const float4v*)(src + idx);
    float4v b = *(const float4v*)(src + idx + 4);
    ushort8 o;
    #pragma unroll
    for (int j = 0; j < 4; ++j) { o[j] = f2bf(a[j]); o[j + 4] = f2bf(b[j]); }
    *(ushort8*)dst = o;
}

// ---------------------------------------------------------------------------
// cvt4: Q,K,V fp32 -> bf16 slabs, + Wq/Wo -> Wb fused (y==3 blocks).
// grid (NBD/2048, 4) x 256. Path A.
// ---------------------------------------------------------------------------
__global__ __launch_bounds__(256) void cvt4(
    const float* __restrict__ Q, const float* __restrict__ K,
    const float* __restrict__ V, const float* __restrict__ Wq,
    const float* __restrict__ Wo, u16* __restrict__ out,
    u16* __restrict__ wb)
{
    const int y = blockIdx.y;
    if (y == 3) {                      // weight conversion: 2*D*D elems
        if (blockIdx.x >= 256) return; // 256 blocks * 2048 = 524,288
        const int idx = (blockIdx.x * 256 + threadIdx.x) * 8;
        const bool hi = idx >= D_ * D_;     // no straddle: 2048 | D*D
        const float* src = hi ? Wo : Wq;
        const int off = hi ? idx - D_ * D_ : idx;
        float4v a = *(const float4v*)(src + off);
        float4v b = *(const float4v*)(src + off + 4);
        ushort8 o;
        #pragma unroll
        for (int j = 0; j < 4; ++j) { o[j] = f2bf(a[j]); o[j + 4] = f2bf(b[j]); }
        *(ushort8*)(wb + idx) = o;
        return;
    }
    const size_t NBD = (size_t)B_ * N_ * D_;
    const float* src = (y == 0) ? Q : ((y == 1) ? K : V);
    u16* dst = out + (size_t)y * NBD;
    size_t idx = ((size_t)blockIdx.x * 256 + threadIdx.x) * 8;
    float4v a = *(const float4v*)(src + idx);
    float4v b = *(const float4v*)(src + idx + 4);
    ushort8 o;
    #pragma unroll
    for (int j = 0; j < 4; ++j) { o[j] = f2bf(a[j]); o[j + 4] = f2bf(b[j]); }
    *(ushort8*)(dst + idx) = o;
}

// ---------------------------------------------------------------------------
// shared epilogue for proj1 variants: bf16 out, z==2 -> transposed Vpt.
// ---------------------------------------------------------------------------
__device__ __forceinline__ void proj1_store(
    float4v (&acc)[4][4], const float* bias, u16* C0,
    int z, int m0, int e0, int wr, int wc, int lane16, int quad)
{
    float bj[4];
    #pragma unroll
    for (int j = 0; j < 4; ++j) bj[j] = bias[e0 + wc + j * 16 + lane16];

    if (z == 2) {   // transposed store: Vpt[b][e][n]
        u16* C = C0 + 2 * (size_t)B_ * N_ * D_;
        #pragma unroll
        for (int i = 0; i < 4; ++i) {
            int mrow = m0 + wr + i * 16 + quad * 4;
            int bb = mrow >> 11, nb = mrow & (N_ - 1);
            #pragma unroll
            for (int j = 0; j < 4; ++j) {
                int e = e0 + wc + j * 16 + lane16;
                us4 o;
                #pragma unroll
                for (int r = 0; r < 4; ++r) o[r] = f2bf(acc[i][j][r] + bj[j]);
                *(us4*)(C + (size_t)(bb * D_ + e) * N_ + nb) = o;
            }
        }
    } else {
        u16* C = C0 + (size_t)z * (size_t)B_ * N_ * D_;
        #pragma unroll
        for (int i = 0; i < 4; ++i)
            #pragma unroll
            for (int j = 0; j < 4; ++j) {
                int e = e0 + wc + j * 16 + lane16;
                #pragma unroll
                for (int r = 0; r < 4; ++r) {
                    int mrow = m0 + wr + i * 16 + quad * 4 + r;
                    C[(size_t)mrow * D_ + e] = f2bf(acc[i][j][r] + bj[j]);
                }
            }
    }
}

// ---------------------------------------------------------------------------
// proj1g (Path A): Xp[z] = Xb[z] @ Wq^T + bq, all inputs bf16, all staging
// via gload. TRIPLE-buffered As/Bs (48KB): per K-step: VM(4); BARRIER;
// ds_read frags; issue stage(c+2); 16 MFMA. grid 768 (3 blocks/CU).
// ---------------------------------------------------------------------------
__global__ __launch_bounds__(256) void proj1g(
    const u16* __restrict__ Xb, const u16* __restrict__ Wb,
    const float* __restrict__ bias, u16* __restrict__ C0)
{
    __shared__ u16 As[3][128][32];
    __shared__ u16 Bs[3][128][32];

    const int t = threadIdx.x;
    const int flat = blockIdx.x;
    const int xcd = flat & 7, rr = flat >> 3;
    const int eb = rr & 3, g = rr >> 2;
    const int zm = xcd + 8 * g;          // 0 .. 191
    const int z  = zm >> 6;
    const int e0 = eb * 128;
    const int m0 = (zm & 63) * 128;

    const u16* X = Xb + (size_t)z * ((size_t)B_ * N_ * D_);
    const int w = t >> 6, l = t & 63;
    const int lane16 = l & 15, quad = l >> 4;
    const int wr = (w >> 1) * 64;
    const int wc = (w & 1) * 64;

    const int arow = l >> 2, acol = (l & 3) * 8;   // gload source lane map

    float4v acc[4][4];
    #pragma unroll
    for (int i = 0; i < 4; ++i)
        #pragma unroll
        for (int j = 0; j < 4; ++j)
            acc[i][j] = (float4v){0.f, 0.f, 0.f, 0.f};

#define P1_STAGE(buf, k0) do { \
        _Pragma("unroll") \
        for (int i = 0; i < 2; ++i) { \
            int r0 = w * 32 + i * 16; \
            gload_lds16(X + (size_t)(m0 + r0 + arow) * 512 + (k0) + acol, \
                        &As[buf][r0][0]); \
        } \
        _Pragma("unroll") \
        for (int i = 0; i < 2; ++i) { \
            int r0 = w * 32 + i * 16; \
            gload_lds16(Wb + (size_t)(e0 + r0 + arow) * 512 + (k0) + acol, \
                        &Bs[buf][r0][0]); \
        } } while (0)

    P1_STAGE(0, 0);
    P1_STAGE(1, 32);

    #pragma unroll
    for (int c = 0; c < 16; ++c) {
        const int cur = c % 3;
        if (c < 15) { WAIT_VM(4); } else { WAIT_VM(0); }
        BARRIER;

        short8 af[4], bfr[4];
        #pragma unroll
        for (int i = 0; i < 4; ++i)
            af[i] = *(const short8*)&As[cur][wr + i * 16 + lane16][quad * 8];
        #pragma unroll
        for (int j = 0; j < 4; ++j)
            bfr[j] = *(const short8*)&Bs[cur][wc + j * 16 + lane16][quad * 8];

        if (c + 2 < 16) P1_STAGE((c + 2) % 3, (c + 2) * 32);

        __builtin_amdgcn_s_setprio(1);
        #pragma unroll
        for (int i = 0; i < 4; ++i)
            #pragma unroll
            for (int j = 0; j < 4; ++j)
                acc[i][j] = __builtin_amdgcn_mfma_f32_16x16x32_bf16(
                    af[i], bfr[j], acc[i][j], 0, 0, 0);
        __builtin_amdgcn_s_setprio(0);
    }
#undef P1_STAGE

    proj1_store(acc, bias, C0, z, m0, e0, wr, wc, lane16, quad);
}

// ---------------------------------------------------------------------------
// proj1f (Path B): X fp32, A staged via reg-prefetch, B via gload dbuf.
// ---------------------------------------------------------------------------
__global__ __launch_bounds__(256) void proj1f(
    const float* __restrict__ X0, const float* __restrict__ X1,
    const float* __restrict__ X2, const u16* __restrict__ Wb,
    const float* __restrict__ bias, u16* __restrict__ C0)
{
    __shared__ u16 As[2][128][32];
    __shared__ u16 Bs[2][128][32];

    const int t = threadIdx.x;
    const int flat = blockIdx.x;
    const int xcd = flat & 7, rr = flat >> 3;
    const int eb = rr & 3, g = rr >> 2;
    const int zm = xcd + 8 * g;
    const int z  = zm >> 6;
    const int e0 = eb * 128;
    const int m0 = (zm & 63) * 128;

    const float* X = (z == 0) ? X0 : ((z == 1) ? X1 : X2);
    const int w = t >> 6, l = t & 63;
    const int lane16 = l & 15, quad = l >> 4;
    const int wr = (w >> 1) * 64;
    const int wc = (w & 1) * 64;
    const int arow = l >> 2, acol = (l & 3) * 8;

    const int xrow = t >> 2, xc8 = (t & 3) * 8;

    float4v acc[4][4];
    #pragma unroll
    for (int i = 0; i < 4; ++i)
        #pragma unroll
        for (int j = 0; j < 4; ++j)
            acc[i][j] = (float4v){0.f, 0.f, 0.f, 0.f};

    float4v xr[2][2][2];

#define P1F_LOADA(k0) do { \
        _Pragma("unroll") \
        for (int i = 0; i < 2; ++i) { \
            const float* xp = X + (size_t)(m0 + xrow + i * 64) * 512 + (k0) + xc8; \
            xr[i][0][0] = *(const float4v*)xp; \
            xr[i][0][1] = *(const float4v*)(xp + 4); \
        } } while (0)

#define P1F_STAGEB(buf, k0) do { \
        _Pragma("unroll") \
        for (int i = 0; i < 2; ++i) { \
            int r0 = w * 32 + i * 16; \
            gload_lds16(Wb + (size_t)(e0 + r0 + arow) * 512 + (k0) + acol, \
                        &Bs[buf][r0][0]); \
        } } while (0)

    P1F_LOADA(0);
    P1F_STAGEB(0, 0);

    #pragma unroll
    for (int c = 0; c < 16; ++c) {
        const int cur = c & 1;
        WAIT_VM(0);

        #pragma unroll
        for (int i = 0; i < 2; ++i) {
            ushort8 o;
            #pragma unroll
            for (int j = 0; j < 4; ++j) {
                o[j]     = f2bf_fast(xr[i][0][0][j]);
                o[j + 4] = f2bf_fast(xr[i][0][1][j]);
            }
            *(ushort8*)&As[cur][xrow + i * 64][xc8] = o;
        }
        WAIT_LGKM0;
        BARRIER;

        short8 af[4], bfr[4];
        #pragma unroll
        for (int i = 0; i < 4; ++i)
            af[i] = *(const short8*)&As[cur][wr + i * 16 + lane16][quad * 8];
        #pragma unroll
        for (int j = 0; j < 4; ++j)
            bfr[j] = *(const short8*)&Bs[cur][wc + j * 16 + lane16][quad * 8];

        if (c + 1 < 16) {
            P1F_LOADA((c + 1) * 32);
            P1F_STAGEB(cur ^ 1, (c + 1) * 32);
        }

        __builtin_amdgcn_s_setprio(1);
        #pragma unroll
        for (int i = 0; i < 4; ++i)
            #pragma unroll
            for (int j = 0; j < 4; ++j)
                acc[i][j] = __builtin_amdgcn_mfma_f32_16x16x32_bf16(
                    af[i], bfr[j], acc[i][j], 0, 0, 0);
        __builtin_amdgcn_s_setprio(0);
    }
#undef P1F_LOADA
#undef P1F_STAGEB

    proj1_store(acc, bias, C0, z, m0, e0, wr, wc, lane16, quad);
}

// ---------------------------------------------------------------------------
// proj2p: out[8192,512] = (P0+P1) @ Wo^T + bo, fp32 out. 128x64 tile,
// 512 blocks = 2 blocks/CU. A reg-prefetch, B gload dbuf, 1 barrier/K-step.
// ---------------------------------------------------------------------------
__global__ __launch_bounds__(256) void proj2p(
    const u16* __restrict__ P0, const u16* __restrict__ P1,
    const u16* __restrict__ Wv, const float* __restrict__ bias,
    float* __restrict__ C)
{
    __shared__ u16 As[2][128][32];
    __shared__ u16 Bs[2][64][32];

    const int t = threadIdx.x;
    const int flat = blockIdx.x;
    const int xcd = flat & 7, rr = flat >> 3;
    const int eb = rr & 7, g = rr >> 3;
    const int m0 = (xcd + 8 * g) * 128;
    const int e0 = eb * 64;

    const int w = t >> 6, l = t & 63;
    const int lane16 = l & 15, quad = l >> 4;
    const int wr = (w >> 1) * 64;
    const int wc = (w & 1) * 32;
    const int arow = l >> 2, acol = (l & 3) * 8;
    const int xrow = t >> 2, xc8 = (t & 3) * 8;

    float4v acc[4][2];
    #pragma unroll
    for (int i = 0; i < 4; ++i)
        #pragma unroll
        for (int j = 0; j < 2; ++j)
            acc[i][j] = (float4v){0.f, 0.f, 0.f, 0.f};

    ushort8 pa[2], pb[2];

#define P2_LOADP(k0) do { \
        _Pragma("unroll") \
        for (int i = 0; i < 2; ++i) { \
            size_t gi = (size_t)(m0 + xrow + i * 64) * 512 + (k0) + xc8; \
            pa[i] = *(const ushort8*)(P0 + gi); \
            pb[i] = *(const ushort8*)(P1 + gi); \
        } } while (0)

    P2_LOADP(0);
    gload_lds16(Wv + (size_t)(e0 + w * 16 + arow) * 512 + 0 + acol, &Bs[0][w * 16][0]);

    #pragma unroll
    for (int c = 0; c < 16; ++c) {
        const int cur = c & 1;
        WAIT_VM(0);

        #pragma unroll
        for (int i = 0; i < 2; ++i) {
            ushort8 o;
            #pragma unroll
            for (int j = 0; j < 8; ++j)
                o[j] = f2bf(bf2f(pa[i][j]) + bf2f(pb[i][j]));
            *(ushort8*)&As[cur][xrow + i * 64][xc8] = o;
        }
        WAIT_LGKM0;
        BARRIER;

        short8 af[4], bfr[2];
        #pragma unroll
        for (int i = 0; i < 4; ++i)
            af[i] = *(const short8*)&As[cur][wr + i * 16 + lane16][quad * 8];
        #pragma unroll
        for (int j = 0; j < 2; ++j)
            bfr[j] = *(const short8*)&Bs[cur][wc + j * 16 + lane16][quad * 8];

        if (c + 1 < 16) {
            P2_LOADP((c + 1) * 32);
            gload_lds16(Wv + (size_t)(e0 + w * 16 + arow) * 512 + (c + 1) * 32 + acol,
                        &Bs[cur ^ 1][w * 16][0]);
        }

        __builtin_amdgcn_s_setprio(1);
        #pragma unroll
        for (int i = 0; i < 4; ++i)
            #pragma unroll
            for (int j = 0; j < 2; ++j)
                acc[i][j] = __builtin_amdgcn_mfma_f32_16x16x32_bf16(
                    af[i], bfr[j], acc[i][j], 0, 0, 0);
        __builtin_amdgcn_s_setprio(0);
    }
#undef P2_LOADP

    float bj[2];
    #pragma unroll
    for (int j = 0; j < 2; ++j) bj[j] = bias[e0 + wc + j * 16 + lane16];

    #pragma unroll
    for (int i = 0; i < 4; ++i)
        #pragma unroll
        for (int j = 0; j < 2; ++j) {
            int e = e0 + wc + j * 16 + lane16;
            #pragma unroll
            for (int r = 0; r < 4; ++r) {
                int mrow = m0 + wr + i * 16 + quad * 4 + r;
                C[(size_t)mrow * D_ + e] = acc[i][j][r] + bj[j];
            }
        }
}

// ---------------------------------------------------------------------------
// attn v9: swapped-QK register-P. 512 thr = 8 waves (ns owns 16 n-rows, ms
// splits the 32-m chunk; heads assigned: wave ms PVs heads ms*4..ms*4+3).
// Per chunk c (2 barriers, counted vmcnt, ledger identical to v8):
//   QK(c) swapped: sacc[h] = mfma(kf, qfrag[h]) -> S^T (m=quad*4+r, n=lane16)
//   VM(4) drain V(c); commit vreg -> Vs
//   softmax (tree) -> own-assigned heads packed to pa[4] (short4, regs);
//     partner-assigned heads -> Px[ns][ms][hh][n][m] (16 scalar writes)
//   issue V(c+1); LGKM0; BAR1
//   issue Kg(c+2) -> Ks[cur]
//   PV: per assigned head hh: pa' = Px[ns][ms^1][hh] (8B); per dt:
//     aacc[hh][dt] += mfma16(pa[hh], vf_own) + mfma16(pa', vf_par)
//   VM(8) drain Kg(c+1); LGKM0; BAR2
// aacc[4][4] covers head ms*4+hh x all 4 d-tiles, both halves -> complete;
// store direct, no reduction. LDS = 66,560 + 36,864 + 18,432 = 121,856 B.
// ---------------------------------------------------------------------------
__global__ __launch_bounds__(512, 2) void attn_mfma9(
    const u16* __restrict__ Qp, const u16* __restrict__ Kp,
    const u16* __restrict__ Vpt, u16* __restrict__ A0)
{
    __shared__ u16 Ks[2][32][520];       // 66,560 B double-buffered K
    __shared__ u16 Vs[512][36];          // 36,864 B (stride-36: clean banks)
    __shared__ u16 Px[4][2][4][16][18];  // 18,432 B partner-head P exchange

    const int t = threadIdx.x;
    const int w = t >> 6, l = t & 63;
    const int lane16 = l & 15, quad = l >> 4;
    const int ns = w >> 1, ms = w & 1;

    const int flat = blockIdx.x;
    const int xcd  = flat & 7;
    const int b = xcd >> 1;            // (b, z) pinned to one XCD
    const int z = xcd & 1;
    const int n0 = (flat >> 3) * 64 + ns * 16;   // this wave-pair's 16 rows
    const int seg  = N_ / 2;
    const int mbeg = z * seg;
    u16* A = A0 + (size_t)z * ((size_t)B_ * N_ * D_);

    const u16* Kb = Kp + (size_t)b * N_ * D_;
    const int vd0 = t >> 2, vpart = (t & 3) * 8;
    const u16* Vsrc = Vpt + (size_t)(b * D_) * N_ + vpart;

    // Q fragments: 8 heads x k=64 (B-operand of swapped QK; same layout)
    short8 qfrag[8][2];
    {
        const u16* qb = Qp + ((size_t)(b * N_ + n0 + lane16) * D_ + quad * 8);
        #pragma unroll
        for (int h = 0; h < 8; ++h)
            #pragma unroll
            for (int dc = 0; dc < 2; ++dc)
                qfrag[h][dc] = *(const short8*)(qb + h * 64 + dc * 32);
    }

    float4v aacc[4][4];                // own 4 heads x 4 d-tiles (64 regs)
    #pragma unroll
    for (int hh = 0; hh < 4; ++hh)
        #pragma unroll
        for (int dt = 0; dt < 4; ++dt)
            aacc[hh][dt] = (float4v){0.f, 0.f, 0.f, 0.f};

    ushort8 vreg[4];                   // V prefetch registers (16 VGPRs)
    const int nch = seg / 32;          // 32 chunks
    const int hbase = ms * 4;          // own-assigned heads
    const int pbase = (ms ^ 1) * 4;    // partner-assigned heads (we write)

    // ---- prologue: Kg(0), Vl(0), Kg(1); drain Kg(0); barrier ----
    #pragma unroll
    for (int i = 0; i < 4; ++i)
        gload_lds16(Kb + (size_t)(mbeg + w * 4 + i) * D_ + l * 8,
                    &Ks[0][w * 4 + i][0]);
    #pragma unroll
    for (int i = 0; i < 4; ++i)
        vreg[i] = *(const ushort8*)(Vsrc + (size_t)(i * 128 + vd0) * N_ + mbeg);
    #pragma unroll
    for (int i = 0; i < 4; ++i)
        gload_lds16(Kb + (size_t)(mbeg + 32 + w * 4 + i) * D_ + l * 8,
                    &Ks[1][w * 4 + i][0]);
    WAIT_VM(8);            // drain Kg(0); Vl(0)+Kg(1) stay in flight
    BARRIER;               // all waves' Kg(0) landed

    for (int c = 0; c < nch; ++c) {
        const int cur = c & 1;
        const int mc  = mbeg + c * 32;

        // ---- QK^T swapped (S^T): batched kf loads per 4-head group ----
        float4v sacc[8];
        #pragma unroll
        for (int h = 0; h < 8; ++h) sacc[h] = (float4v){0.f, 0.f, 0.f, 0.f};
        #pragma unroll
        for (int g2 = 0; g2 < 2; ++g2) {
            short8 kf[4][2];
            #pragma unroll
            for (int hh = 0; hh < 4; ++hh)
                #pragma unroll
                for (int dc = 0; dc < 2; ++dc)
                    kf[hh][dc] = *(const short8*)
                        &Ks[cur][ms * 16 + lane16]
                           [(g2 * 4 + hh) * 64 + dc * 32 + quad * 8];
            __builtin_amdgcn_s_setprio(1);
            #pragma unroll
            for (int hh = 0; hh < 4; ++hh)
                #pragma unroll
                for (int dc = 0; dc < 2; ++dc)
                    sacc[g2 * 4 + hh] = __builtin_amdgcn_mfma_f32_16x16x32_bf16(
                        kf[hh][dc], qfrag[g2 * 4 + hh][dc], sacc[g2 * 4 + hh],
                        0, 0, 0);
            __builtin_amdgcn_s_setprio(0);
        }

        // ---- drain own V-reg loads(c); commit V(c) to Vs ----
        if (c < nch - 1) { WAIT_VM(4); } else { WAIT_VM(0); }
        #pragma unroll
        for (int i = 0; i < 4; ++i)
            *(ushort8*)&Vs[i * 128 + vd0][vpart] = vreg[i];

        // ---- softmax (per lane elem: n=lane16, m=ms*16+quad*4+r) ----
        float inv[4];
        #pragma unroll
        for (int r = 0; r < 4; ++r) {
            #pragma unroll
            for (int h = 0; h < 8; ++h)
                sacc[h][r] = __expf(sacc[h][r] * 0.125f);   // 1/sqrt(64)
            float s01 = sacc[0][r] + sacc[1][r], s23 = sacc[2][r] + sacc[3][r];
            float s45 = sacc[4][r] + sacc[5][r], s67 = sacc[6][r] + sacc[7][r];
            inv[r] = __builtin_amdgcn_rcpf((s01 + s23) + (s45 + s67));
        }
        // own-assigned heads -> registers (k=16 A-frag: k = quad*4 + r)
        short4v pa[4];
        #pragma unroll
        for (int hh = 0; hh < 4; ++hh)
            #pragma unroll
            for (int r = 0; r < 4; ++r)
                pa[hh][r] = (short)f2bf_fast(sacc[hbase + hh][r] * inv[r]);
        // partner-assigned heads -> Px
        #pragma unroll
        for (int hh = 0; hh < 4; ++hh)
            #pragma unroll
            for (int r = 0; r < 4; ++r)
                Px[ns][ms][hh][lane16][quad * 4 + r] =
                    f2bf_fast(sacc[pbase + hh][r] * inv[r]);

        // ---- prefetch V(c+1) into registers ----
        if (c + 1 < nch) {
            #pragma unroll
            for (int i = 0; i < 4; ++i)
                vreg[i] = *(const ushort8*)
                    (Vsrc + (size_t)(i * 128 + vd0) * N_ + mc + 32);
        }

        // ---- Px+Vs visible; VMEM prefetches stay in flight ----
        WAIT_LGKM0;
        BARRIER;

        // ---- prefetch K(c+2) into the Ks buffer QK(c) just freed ----
        if (c + 2 < nch) {
            #pragma unroll
            for (int i = 0; i < 4; ++i)
                gload_lds16(Kb + (size_t)(mc + 64 + w * 4 + i) * D_ + l * 8,
                            &Ks[cur][w * 4 + i][0]);
        }

        // ---- PV: own heads x 4 d-tiles; own half from regs, partner via Px
        __builtin_amdgcn_s_setprio(1);
        #pragma unroll
        for (int hh = 0; hh < 4; ++hh) {
            const int hrow = (hbase + hh) * 64;
            short4v pap = *(const short4v*)&Px[ns][ms ^ 1][hh][lane16][quad * 4];
            #pragma unroll
            for (int dt = 0; dt < 4; ++dt) {
                const u16* vrow = &Vs[hrow + dt * 16 + lane16][0];
                short4v vfo = *(const short4v*)(vrow + ms * 16 + quad * 4);
                short4v vfp = *(const short4v*)(vrow + (ms ^ 1) * 16 + quad * 4);
                aacc[hh][dt] = mfma16(pa[hh], vfo, aacc[hh][dt]);
                aacc[hh][dt] = mfma16(pap,   vfp, aacc[hh][dt]);
            }
        }
        __builtin_amdgcn_s_setprio(0);

        // ---- drain own Kg(c+1) before barrier -> QK(c+1) safe ----
        if (c < nch - 1) {
            if (c + 2 < nch) { WAIT_VM(8); } else { WAIT_VM(4); }
            WAIT_LGKM0;
            BARRIER;
        }
    }

    // ---- store partial A (bf16): own 4 heads x all 512 d, complete ----
    #pragma unroll
    for (int hh = 0; hh < 4; ++hh)
        #pragma unroll
        for (int dt = 0; dt < 4; ++dt)
            #pragma unroll
            for (int r = 0; r < 4; ++r) {
                const int n = n0 + quad * 4 + r;
                const int d = (hbase + hh) * 64 + dt * 16 + lane16;
                A[(size_t)(b * N_ + n) * D_ + d] = f2bf(aacc[hh][dt][r]);
            }
}

// ---------------------------------------------------------------------------
extern "C" void kernel_launch(void* const* d_in, const int* in_sizes, int n_in,
                              void* d_out, int out_size, void* d_ws, size_t ws_size,
                              hipStream_t stream)
{
    const float* Q  = (const float*)d_in[0];
    const float* K  = (const float*)d_in[1];
    const float* V  = (const float*)d_in[2];
    const float* Wq = (const float*)d_in[3];
    const float* bq = (const float*)d_in[4];
    const float* Wo = (const float*)d_in[5];
    const float* bo = (const float*)d_in[6];
    float* out = (float*)d_out;
    u16*   ws  = (u16*)d_ws;

    const size_t NBD = (size_t)B_ * N_ * D_;   // 4,194,304

    const size_t need6 = (6 * NBD + 2 * (size_t)D_ * D_) * sizeof(u16); // 51.4 MB

    if (ws_size >= need6) {
        // Path A: bf16-ify inputs once; proj1 all-gload pipelined.
        u16* S0 = ws;
        u16* S1 = ws + NBD;
        u16* S3 = ws + 3 * NBD;
        u16* Wb = ws + 6 * NBD;            // [Wqb | Wob]

        cvt4<<<dim3((unsigned)(NBD / 2048), 4), dim3(256), 0, stream>>>(
            Q, K, V, Wq, Wo, S0, Wb);

        proj1g<<<dim3(768), dim3(256), 0, stream>>>(S0, Wb, bq, S3);

        attn_mfma9<<<dim3(256), dim3(512), 0, stream>>>(
            S3, S3 + NBD, S3 + 2 * NBD, S0);   // partials -> S0, S1

        proj2p<<<dim3(512), dim3(256), 0, stream>>>(
            S0, S1, Wb + (size_t)D_ * D_, bo, out);
    } else {
        // Path B (43.0 MB): fp32-X reg-prefetch staging in proj1.
        u16* Qp  = ws;
        u16* Kp  = ws + NBD;
        u16* Vpt = ws + 2 * NBD;
        u16* Pa  = ws + 3 * NBD;
        u16* Pb  = ws + 4 * NBD;
        u16* Wb  = ws + 5 * NBD;

        wconv<<<dim3(128, 2), dim3(256), 0, stream>>>(Wq, Wo, Wb);

        proj1f<<<dim3(768), dim3(256), 0, stream>>>(Q, K, V, Wb, bq, Qp);

        attn_mfma9<<<dim3(256), dim3(512), 0, stream>>>(Qp, Kp, Vpt, Pa);

        proj2p<<<dim3(512), dim3(256), 0, stream>>>(
            Pa, Pb, Wb + (size_t)D_ * D_, bo, out);
    }
}

// Round 10
// 221.104 us; speedup vs baseline: 4.0772x; 4.0772x over previous
//
#include <hip/hip_runtime.h>
#include <hip/hip_bf16.h>

// B,N,D,H = 4,2048,512,8 (DK=64). fp32 I/O; bf16 intermediates in ws.
// v13 = v11 (cvt4 + proj1g + proj2p pipelined GEMMs) with attn v10:
// attn v10 = v8 (98.6us proven) + swapped QK^T ONLY for its layout win:
// mfma(K,Q) -> S^T puts each thread's 4 P values at contiguous m-slots of
// ONE n-row -> Ps commit becomes 8 x us4 vector writes (was 32 scalar
// ds_write_b16 + addr VALU). PV/k=32, aacc[8][2], Ps geometry, vmcnt
// ledger all byte-identical to v8. No new register structures, no inline
// asm (v9's 343MB scratch-spill lesson: reg-P + asm mfma16 = allocator
// death; this keeps the swap's write-vectorization without the pressure).
#define B_  4
#define N_  2048
#define D_  512
#define H_  8

typedef unsigned short u16;
typedef __attribute__((ext_vector_type(8))) unsigned short ushort8;
typedef __attribute__((ext_vector_type(4))) unsigned short us4;
typedef __attribute__((ext_vector_type(8))) short short8;
typedef __attribute__((ext_vector_type(4))) float float4v;

__device__ __forceinline__ float bf2f(u16 u) {
    union { unsigned int i; float f; } v;
    v.i = ((unsigned int)u) << 16;
    return v.f;
}
__device__ __forceinline__ u16 f2bf(float f) {          // RNE
    union { float f; unsigned int i; } v;
    v.f = f;
    unsigned int r = v.i + 0x7FFFu + ((v.i >> 16) & 1u);
    return (u16)(r >> 16);
}
__device__ __forceinline__ u16 f2bf_fast(float f) {     // round-half-up
    union { float f; unsigned int i; } v;
    v.f = f;
    return (u16)((v.i + 0x8000u) >> 16);
}

// async global->LDS, 16B/lane, dest = wave-uniform base + lane*16 (m104 rule)
__device__ __forceinline__ void gload_lds16(const void* g, void* l) {
    __builtin_amdgcn_global_load_lds(
        (const __attribute__((address_space(1))) unsigned int*)g,
        (__attribute__((address_space(3))) unsigned int*)l, 16, 0, 0);
}

#define WAIT_VM(N) do { \
    asm volatile("s_waitcnt vmcnt(" #N ")" ::: "memory"); \
    __builtin_amdgcn_sched_barrier(0); } while (0)
#define WAIT_LGKM0 do { \
    asm volatile("s_waitcnt lgkmcnt(0)" ::: "memory"); \
    __builtin_amdgcn_sched_barrier(0); } while (0)
#define BARRIER do { \
    __builtin_amdgcn_s_barrier(); \
    __builtin_amdgcn_sched_barrier(0); } while (0)

// ---------------------------------------------------------------------------
// wconv: Wq,Wo fp32 -> bf16, out = [Wqb | Wob]. grid (128, 2) x 256. Path B.
// ---------------------------------------------------------------------------
__global__ __launch_bounds__(256) void wconv(
    const float* __restrict__ Wq, const float* __restrict__ Wo,
    u16* __restrict__ out)
{
    const int idx = (blockIdx.x * 256 + threadIdx.x) * 8;
    const float* src = blockIdx.y ? Wo : Wq;
    u16* dst = out + (size_t)blockIdx.y * (D_ * D_) + idx;
    float4v a = *(const float4v*)(src + idx);
    float4v b = *(const float4v*)(src + idx + 4);
    ushort8 o;
    #pragma unroll
    for (int j = 0; j < 4; ++j) { o[j] = f2bf(a[j]); o[j + 4] = f2bf(b[j]); }
    *(ushort8*)dst = o;
}

// ---------------------------------------------------------------------------
// cvt4: Q,K,V fp32 -> bf16 slabs, + Wq/Wo -> Wb fused (y==3 blocks).
// grid (NBD/2048, 4) x 256. Path A.
// ---------------------------------------------------------------------------
__global__ __launch_bounds__(256) void cvt4(
    const float* __restrict__ Q, const float* __restrict__ K,
    const float* __restrict__ V, const float* __restrict__ Wq,
    const float* __restrict__ Wo, u16* __restrict__ out,
    u16* __restrict__ wb)
{
    const int y = blockIdx.y;
    if (y == 3) {                      // weight conversion: 2*D*D elems
        if (blockIdx.x >= 256) return; // 256 blocks * 2048 = 524,288
        const int idx = (blockIdx.x * 256 + threadIdx.x) * 8;
        const bool hi = idx >= D_ * D_;     // no straddle: 2048 | D*D
        const float* src = hi ? Wo : Wq;
        const int off = hi ? idx - D_ * D_ : idx;
        float4v a = *(const float4v*)(src + off);
        float4v b = *(const float4v*)(src + off + 4);
        ushort8 o;
        #pragma unroll
        for (int j = 0; j < 4; ++j) { o[j] = f2bf(a[j]); o[j + 4] = f2bf(b[j]); }
        *(ushort8*)(wb + idx) = o;
        return;
    }
    const size_t NBD = (size_t)B_ * N_ * D_;
    const float* src = (y == 0) ? Q : ((y == 1) ? K : V);
    u16* dst = out + (size_t)y * NBD;
    size_t idx = ((size_t)blockIdx.x * 256 + threadIdx.x) * 8;
    float4v a = *(const float4v*)(src + idx);
    float4v b = *(const float4v*)(src + idx + 4);
    ushort8 o;
    #pragma unroll
    for (int j = 0; j < 4; ++j) { o[j] = f2bf(a[j]); o[j + 4] = f2bf(b[j]); }
    *(ushort8*)(dst + idx) = o;
}

// ---------------------------------------------------------------------------
// shared epilogue for proj1 variants: bf16 out, z==2 -> transposed Vpt.
// ---------------------------------------------------------------------------
__device__ __forceinline__ void proj1_store(
    float4v (&acc)[4][4], const float* bias, u16* C0,
    int z, int m0, int e0, int wr, int wc, int lane16, int quad)
{
    float bj[4];
    #pragma unroll
    for (int j = 0; j < 4; ++j) bj[j] = bias[e0 + wc + j * 16 + lane16];

    if (z == 2) {   // transposed store: Vpt[b][e][n]
        u16* C = C0 + 2 * (size_t)B_ * N_ * D_;
        #pragma unroll
        for (int i = 0; i < 4; ++i) {
            int mrow = m0 + wr + i * 16 + quad * 4;
            int bb = mrow >> 11, nb = mrow & (N_ - 1);
            #pragma unroll
            for (int j = 0; j < 4; ++j) {
                int e = e0 + wc + j * 16 + lane16;
                us4 o;
                #pragma unroll
                for (int r = 0; r < 4; ++r) o[r] = f2bf(acc[i][j][r] + bj[j]);
                *(us4*)(C + (size_t)(bb * D_ + e) * N_ + nb) = o;
            }
        }
    } else {
        u16* C = C0 + (size_t)z * (size_t)B_ * N_ * D_;
        #pragma unroll
        for (int i = 0; i < 4; ++i)
            #pragma unroll
            for (int j = 0; j < 4; ++j) {
                int e = e0 + wc + j * 16 + lane16;
                #pragma unroll
                for (int r = 0; r < 4; ++r) {
                    int mrow = m0 + wr + i * 16 + quad * 4 + r;
                    C[(size_t)mrow * D_ + e] = f2bf(acc[i][j][r] + bj[j]);
                }
            }
    }
}

// ---------------------------------------------------------------------------
// proj1g (Path A): Xp[z] = Xb[z] @ Wq^T + bq, all inputs bf16, all staging
// via gload. TRIPLE-buffered As/Bs (48KB): per K-step: VM(4); BARRIER;
// ds_read frags; issue stage(c+2); 16 MFMA. grid 768 (3 blocks/CU).
// ---------------------------------------------------------------------------
__global__ __launch_bounds__(256) void proj1g(
    const u16* __restrict__ Xb, const u16* __restrict__ Wb,
    const float* __restrict__ bias, u16* __restrict__ C0)
{
    __shared__ u16 As[3][128][32];
    __shared__ u16 Bs[3][128][32];

    const int t = threadIdx.x;
    const int flat = blockIdx.x;
    const int xcd = flat & 7, rr = flat >> 3;
    const int eb = rr & 3, g = rr >> 2;
    const int zm = xcd + 8 * g;          // 0 .. 191
    const int z  = zm >> 6;
    const int e0 = eb * 128;
    const int m0 = (zm & 63) * 128;

    const u16* X = Xb + (size_t)z * ((size_t)B_ * N_ * D_);
    const int w = t >> 6, l = t & 63;
    const int lane16 = l & 15, quad = l >> 4;
    const int wr = (w >> 1) * 64;
    const int wc = (w & 1) * 64;

    const int arow = l >> 2, acol = (l & 3) * 8;   // gload source lane map

    float4v acc[4][4];
    #pragma unroll
    for (int i = 0; i < 4; ++i)
        #pragma unroll
        for (int j = 0; j < 4; ++j)
            acc[i][j] = (float4v){0.f, 0.f, 0.f, 0.f};

#define P1_STAGE(buf, k0) do { \
        _Pragma("unroll") \
        for (int i = 0; i < 2; ++i) { \
            int r0 = w * 32 + i * 16; \
            gload_lds16(X + (size_t)(m0 + r0 + arow) * 512 + (k0) + acol, \
                        &As[buf][r0][0]); \
        } \
        _Pragma("unroll") \
        for (int i = 0; i < 2; ++i) { \
            int r0 = w * 32 + i * 16; \
            gload_lds16(Wb + (size_t)(e0 + r0 + arow) * 512 + (k0) + acol, \
                        &Bs[buf][r0][0]); \
        } } while (0)

    P1_STAGE(0, 0);
    P1_STAGE(1, 32);

    #pragma unroll
    for (int c = 0; c < 16; ++c) {
        const int cur = c % 3;
        if (c < 15) { WAIT_VM(4); } else { WAIT_VM(0); }
        BARRIER;

        short8 af[4], bfr[4];
        #pragma unroll
        for (int i = 0; i < 4; ++i)
            af[i] = *(const short8*)&As[cur][wr + i * 16 + lane16][quad * 8];
        #pragma unroll
        for (int j = 0; j < 4; ++j)
            bfr[j] = *(const short8*)&Bs[cur][wc + j * 16 + lane16][quad * 8];

        if (c + 2 < 16) P1_STAGE((c + 2) % 3, (c + 2) * 32);

        __builtin_amdgcn_s_setprio(1);
        #pragma unroll
        for (int i = 0; i < 4; ++i)
            #pragma unroll
            for (int j = 0; j < 4; ++j)
                acc[i][j] = __builtin_amdgcn_mfma_f32_16x16x32_bf16(
                    af[i], bfr[j], acc[i][j], 0, 0, 0);
        __builtin_amdgcn_s_setprio(0);
    }
#undef P1_STAGE

    proj1_store(acc, bias, C0, z, m0, e0, wr, wc, lane16, quad);
}

// ---------------------------------------------------------------------------
// proj1f (Path B): X fp32, A staged via reg-prefetch, B via gload dbuf.
// ---------------------------------------------------------------------------
__global__ __launch_bounds__(256) void proj1f(
    const float* __restrict__ X0, const float* __restrict__ X1,
    const float* __restrict__ X2, const u16* __restrict__ Wb,
    const float* __restrict__ bias, u16* __restrict__ C0)
{
    __shared__ u16 As[2][128][32];
    __shared__ u16 Bs[2][128][32];

    const int t = threadIdx.x;
    const int flat = blockIdx.x;
    const int xcd = flat & 7, rr = flat >> 3;
    const int eb = rr & 3, g = rr >> 2;
    const int zm = xcd + 8 * g;
    const int z  = zm >> 6;
    const int e0 = eb * 128;
    const int m0 = (zm & 63) * 128;

    const float* X = (z == 0) ? X0 : ((z == 1) ? X1 : X2);
    const int w = t >> 6, l = t & 63;
    const int lane16 = l & 15, quad = l >> 4;
    const int wr = (w >> 1) * 64;
    const int wc = (w & 1) * 64;
    const int arow = l >> 2, acol = (l & 3) * 8;

    const int xrow = t >> 2, xc8 = (t & 3) * 8;

    float4v acc[4][4];
    #pragma unroll
    for (int i = 0; i < 4; ++i)
        #pragma unroll
        for (int j = 0; j < 4; ++j)
            acc[i][j] = (float4v){0.f, 0.f, 0.f, 0.f};

    float4v xr[2][2][2];

#define P1F_LOADA(k0) do { \
        _Pragma("unroll") \
        for (int i = 0; i < 2; ++i) { \
            const float* xp = X + (size_t)(m0 + xrow + i * 64) * 512 + (k0) + xc8; \
            xr[i][0][0] = *(const float4v*)xp; \
            xr[i][0][1] = *(const float4v*)(xp + 4); \
        } } while (0)

#define P1F_STAGEB(buf, k0) do { \
        _Pragma("unroll") \
        for (int i = 0; i < 2; ++i) { \
            int r0 = w * 32 + i * 16; \
            gload_lds16(Wb + (size_t)(e0 + r0 + arow) * 512 + (k0) + acol, \
                        &Bs[buf][r0][0]); \
        } } while (0)

    P1F_LOADA(0);
    P1F_STAGEB(0, 0);

    #pragma unroll
    for (int c = 0; c < 16; ++c) {
        const int cur = c & 1;
        WAIT_VM(0);

        #pragma unroll
        for (int i = 0; i < 2; ++i) {
            ushort8 o;
            #pragma unroll
            for (int j = 0; j < 4; ++j) {
                o[j]     = f2bf_fast(xr[i][0][0][j]);
                o[j + 4] = f2bf_fast(xr[i][0][1][j]);
            }
            *(ushort8*)&As[cur][xrow + i * 64][xc8] = o;
        }
        WAIT_LGKM0;
        BARRIER;

        short8 af[4], bfr[4];
        #pragma unroll
        for (int i = 0; i < 4; ++i)
            af[i] = *(const short8*)&As[cur][wr + i * 16 + lane16][quad * 8];
        #pragma unroll
        for (int j = 0; j < 4; ++j)
            bfr[j] = *(const short8*)&Bs[cur][wc + j * 16 + lane16][quad * 8];

        if (c + 1 < 16) {
            P1F_LOADA((c + 1) * 32);
            P1F_STAGEB(cur ^ 1, (c + 1) * 32);
        }

        __builtin_amdgcn_s_setprio(1);
        #pragma unroll
        for (int i = 0; i < 4; ++i)
            #pragma unroll
            for (int j = 0; j < 4; ++j)
                acc[i][j] = __builtin_amdgcn_mfma_f32_16x16x32_bf16(
                    af[i], bfr[j], acc[i][j], 0, 0, 0);
        __builtin_amdgcn_s_setprio(0);
    }
#undef P1F_LOADA
#undef P1F_STAGEB

    proj1_store(acc, bias, C0, z, m0, e0, wr, wc, lane16, quad);
}

// ---------------------------------------------------------------------------
// proj2p: out[8192,512] = (P0+P1) @ Wo^T + bo, fp32 out. 128x64 tile,
// 512 blocks = 2 blocks/CU. A reg-prefetch, B gload dbuf, 1 barrier/K-step.
// ---------------------------------------------------------------------------
__global__ __launch_bounds__(256) void proj2p(
    const u16* __restrict__ P0, const u16* __restrict__ P1,
    const u16* __restrict__ Wv, const float* __restrict__ bias,
    float* __restrict__ C)
{
    __shared__ u16 As[2][128][32];
    __shared__ u16 Bs[2][64][32];

    const int t = threadIdx.x;
    const int flat = blockIdx.x;
    const int xcd = flat & 7, rr = flat >> 3;
    const int eb = rr & 7, g = rr >> 3;
    const int m0 = (xcd + 8 * g) * 128;
    const int e0 = eb * 64;

    const int w = t >> 6, l = t & 63;
    const int lane16 = l & 15, quad = l >> 4;
    const int wr = (w >> 1) * 64;
    const int wc = (w & 1) * 32;
    const int arow = l >> 2, acol = (l & 3) * 8;
    const int xrow = t >> 2, xc8 = (t & 3) * 8;

    float4v acc[4][2];
    #pragma unroll
    for (int i = 0; i < 4; ++i)
        #pragma unroll
        for (int j = 0; j < 2; ++j)
            acc[i][j] = (float4v){0.f, 0.f, 0.f, 0.f};

    ushort8 pa[2], pb[2];

#define P2_LOADP(k0) do { \
        _Pragma("unroll") \
        for (int i = 0; i < 2; ++i) { \
            size_t gi = (size_t)(m0 + xrow + i * 64) * 512 + (k0) + xc8; \
            pa[i] = *(const ushort8*)(P0 + gi); \
            pb[i] = *(const ushort8*)(P1 + gi); \
        } } while (0)

    P2_LOADP(0);
    gload_lds16(Wv + (size_t)(e0 + w * 16 + arow) * 512 + 0 + acol, &Bs[0][w * 16][0]);

    #pragma unroll
    for (int c = 0; c < 16; ++c) {
        const int cur = c & 1;
        WAIT_VM(0);

        #pragma unroll
        for (int i = 0; i < 2; ++i) {
            ushort8 o;
            #pragma unroll
            for (int j = 0; j < 8; ++j)
                o[j] = f2bf(bf2f(pa[i][j]) + bf2f(pb[i][j]));
            *(ushort8*)&As[cur][xrow + i * 64][xc8] = o;
        }
        WAIT_LGKM0;
        BARRIER;

        short8 af[4], bfr[2];
        #pragma unroll
        for (int i = 0; i < 4; ++i)
            af[i] = *(const short8*)&As[cur][wr + i * 16 + lane16][quad * 8];
        #pragma unroll
        for (int j = 0; j < 2; ++j)
            bfr[j] = *(const short8*)&Bs[cur][wc + j * 16 + lane16][quad * 8];

        if (c + 1 < 16) {
            P2_LOADP((c + 1) * 32);
            gload_lds16(Wv + (size_t)(e0 + w * 16 + arow) * 512 + (c + 1) * 32 + acol,
                        &Bs[cur ^ 1][w * 16][0]);
        }

        __builtin_amdgcn_s_setprio(1);
        #pragma unroll
        for (int i = 0; i < 4; ++i)
            #pragma unroll
            for (int j = 0; j < 2; ++j)
                acc[i][j] = __builtin_amdgcn_mfma_f32_16x16x32_bf16(
                    af[i], bfr[j], acc[i][j], 0, 0, 0);
        __builtin_amdgcn_s_setprio(0);
    }
#undef P2_LOADP

    float bj[2];
    #pragma unroll
    for (int j = 0; j < 2; ++j) bj[j] = bias[e0 + wc + j * 16 + lane16];

    #pragma unroll
    for (int i = 0; i < 4; ++i)
        #pragma unroll
        for (int j = 0; j < 2; ++j) {
            int e = e0 + wc + j * 16 + lane16;
            #pragma unroll
            for (int r = 0; r < 4; ++r) {
                int mrow = m0 + wr + i * 16 + quad * 4 + r;
                C[(size_t)mrow * D_ + e] = acc[i][j][r] + bj[j];
            }
        }
}

// ---------------------------------------------------------------------------
// attn v10: v8 structure + swapped QK^T (layout-only change).
// 512 thr = 8 waves (ns owns 16 n-rows, ms splits the 32-m chunk).
// QK(c) swapped: sacc[h] = mfma(kf, qfrag[h]) -> S^T per thread:
//   n = lane16 (fixed), m = ms*16 + quad*4 + r (4 CONTIGUOUS m-slots)
// -> Ps commit per head = ONE us4 vector write at [n=lane16][ms*16+quad*4]
//    (8 x ds_write_b64 total vs v8's 32 x ds_write_b16).
// PV identical to v8: pf = Ps[ns][h][lane16][quad*8] (k=32 A-frag), vf from
// Vs, aacc[8][2]. Pipeline/vmcnt ledger identical to v8:
//   QK -> VM(4)+commit Vs -> softmax -> Ps -> Vl(c+1) -> LGKM0+BAR1 ->
//   Kg(c+2) -> PV -> VM(8)+LGKM0+BAR2.
// Vs/Ps stride 36 u16. LDS 140,288 B. grid 256, flat&7=(b,z).
// ---------------------------------------------------------------------------
__global__ __launch_bounds__(512, 2) void attn_mfma10(
    const u16* __restrict__ Qp, const u16* __restrict__ Kp,
    const u16* __restrict__ Vpt, u16* __restrict__ A0)
{
    __shared__ u16 Ks[2][32][520];     // 66,560 B double-buffered K
    __shared__ u16 Vs[512][36];        // 36,864 B (stride-36: clean banks)
    __shared__ u16 Ps[4][8][16][36];   // 36,864 B pair-shared P [n][m]

    const int t = threadIdx.x;
    const int w = t >> 6, l = t & 63;
    const int lane16 = l & 15, quad = l >> 4;
    const int ns = w >> 1, ms = w & 1;

    const int flat = blockIdx.x;
    const int xcd  = flat & 7;
    const int b = xcd >> 1;            // (b, z) pinned to one XCD
    const int z = xcd & 1;
    const int n0 = (flat >> 3) * 64 + ns * 16;   // this wave-pair's 16 rows
    const int seg  = N_ / 2;
    const int mbeg = z * seg;
    u16* A = A0 + (size_t)z * ((size_t)B_ * N_ * D_);

    const u16* Kb = Kp + (size_t)b * N_ * D_;
    const int vd0 = t >> 2, vpart = (t & 3) * 8;
    const u16* Vsrc = Vpt + (size_t)(b * D_) * N_ + vpart;

    // Q fragments: 8 heads x k=64 (B-operand of swapped QK; same layout)
    short8 qfrag[8][2];
    {
        const u16* qb = Qp + ((size_t)(b * N_ + n0 + lane16) * D_ + quad * 8);
        #pragma unroll
        for (int h = 0; h < 8; ++h)
            #pragma unroll
            for (int dc = 0; dc < 2; ++dc)
                qfrag[h][dc] = *(const short8*)(qb + h * 64 + dc * 32);
    }

    float4v aacc[8][2];                // 8 heads x 2 owned d-tiles (64 regs)
    #pragma unroll
    for (int h = 0; h < 8; ++h)
        #pragma unroll
        for (int dt = 0; dt < 2; ++dt)
            aacc[h][dt] = (float4v){0.f, 0.f, 0.f, 0.f};

    ushort8 vreg[4];                   // V prefetch registers (16 VGPRs)
    const int nch = seg / 32;          // 32 chunks

    // ---- prologue: Kg(0), Vl(0), Kg(1); drain Kg(0); barrier ----
    #pragma unroll
    for (int i = 0; i < 4; ++i)
        gload_lds16(Kb + (size_t)(mbeg + w * 4 + i) * D_ + l * 8,
                    &Ks[0][w * 4 + i][0]);
    #pragma unroll
    for (int i = 0; i < 4; ++i)
        vreg[i] = *(const ushort8*)(Vsrc + (size_t)(i * 128 + vd0) * N_ + mbeg);
    #pragma unroll
    for (int i = 0; i < 4; ++i)
        gload_lds16(Kb + (size_t)(mbeg + 32 + w * 4 + i) * D_ + l * 8,
                    &Ks[1][w * 4 + i][0]);
    WAIT_VM(8);            // drain Kg(0); Vl(0)+Kg(1) stay in flight
    BARRIER;               // all waves' Kg(0) landed

    for (int c = 0; c < nch; ++c) {
        const int cur = c & 1;
        const int mc  = mbeg + c * 32;

        // ---- QK^T swapped (S^T): batched kf loads per 4-head group ----
        float4v sacc[8];
        #pragma unroll
        for (int h = 0; h < 8; ++h) sacc[h] = (float4v){0.f, 0.f, 0.f, 0.f};
        #pragma unroll
        for (int g2 = 0; g2 < 2; ++g2) {
            short8 kf[4][2];
            #pragma unroll
            for (int hh = 0; hh < 4; ++hh)
                #pragma unroll
                for (int dc = 0; dc < 2; ++dc)
                    kf[hh][dc] = *(const short8*)
                        &Ks[cur][ms * 16 + lane16]
                           [(g2 * 4 + hh) * 64 + dc * 32 + quad * 8];
            __builtin_amdgcn_s_setprio(1);
            #pragma unroll
            for (int hh = 0; hh < 4; ++hh)
                #pragma unroll
                for (int dc = 0; dc < 2; ++dc)
                    sacc[g2 * 4 + hh] = __builtin_amdgcn_mfma_f32_16x16x32_bf16(
                        kf[hh][dc], qfrag[g2 * 4 + hh][dc], sacc[g2 * 4 + hh],
                        0, 0, 0);
            __builtin_amdgcn_s_setprio(0);
        }

        // ---- drain own V-reg loads(c); commit V(c) to Vs ----
        if (c < nch - 1) { WAIT_VM(4); } else { WAIT_VM(0); }
        #pragma unroll
        for (int i = 0; i < 4; ++i)
            *(ushort8*)&Vs[i * 128 + vd0][vpart] = vreg[i];

        // ---- softmax (n=lane16, m=ms*16+quad*4+r) -> Ps us4 writes ----
        float inv[4];
        #pragma unroll
        for (int r = 0; r < 4; ++r) {
            #pragma unroll
            for (int h = 0; h < 8; ++h)
                sacc[h][r] = __expf(sacc[h][r] * 0.125f);   // 1/sqrt(64)
            float s01 = sacc[0][r] + sacc[1][r], s23 = sacc[2][r] + sacc[3][r];
            float s45 = sacc[4][r] + sacc[5][r], s67 = sacc[6][r] + sacc[7][r];
            inv[r] = __builtin_amdgcn_rcpf((s01 + s23) + (s45 + s67));
        }
        #pragma unroll
        for (int h = 0; h < 8; ++h) {
            us4 o;
            #pragma unroll
            for (int r = 0; r < 4; ++r)
                o[r] = f2bf_fast(sacc[h][r] * inv[r]);
            *(us4*)&Ps[ns][h][lane16][ms * 16 + quad * 4] = o;
        }

        // ---- prefetch V(c+1) into registers ----
        if (c + 1 < nch) {
            #pragma unroll
            for (int i = 0; i < 4; ++i)
                vreg[i] = *(const ushort8*)
                    (Vsrc + (size_t)(i * 128 + vd0) * N_ + mc + 32);
        }

        // ---- Ps+Vs visible; VMEM prefetches stay in flight ----
        WAIT_LGKM0;
        BARRIER;

        // ---- prefetch K(c+2) into the Ks buffer QK(c) just freed ----
        if (c + 2 < nch) {
            #pragma unroll
            for (int i = 0; i < 4; ++i)
                gload_lds16(Kb + (size_t)(mc + 64 + w * 4 + i) * D_ + l * 8,
                            &Ks[cur][w * 4 + i][0]);
        }

        // ---- PV: batched pf/vf loads per 4 heads (identical to v8) ----
        #pragma unroll
        for (int g2 = 0; g2 < 2; ++g2) {
            short8 pf[4], vf[4][2];
            #pragma unroll
            for (int hh = 0; hh < 4; ++hh) {
                const int h = g2 * 4 + hh;
                pf[hh] = *(const short8*)&Ps[ns][h][lane16][quad * 8];
                #pragma unroll
                for (int dt = 0; dt < 2; ++dt)
                    vf[hh][dt] = *(const short8*)
                        &Vs[h * 64 + (ms * 2 + dt) * 16 + lane16][quad * 8];
            }
            __builtin_amdgcn_s_setprio(1);
            #pragma unroll
            for (int hh = 0; hh < 4; ++hh)
                #pragma unroll
                for (int dt = 0; dt < 2; ++dt)
                    aacc[g2 * 4 + hh][dt] = __builtin_amdgcn_mfma_f32_16x16x32_bf16(
                        pf[hh], vf[hh][dt], aacc[g2 * 4 + hh][dt], 0, 0, 0);
            __builtin_amdgcn_s_setprio(0);
        }

        // ---- drain own Kg(c+1) before barrier -> QK(c+1) safe ----
        if (c < nch - 1) {
            if (c + 2 < nch) { WAIT_VM(8); } else { WAIT_VM(4); }
            WAIT_LGKM0;
            BARRIER;
        }
    }

    // ---- store partial A (bf16), own d-columns only ----
    #pragma unroll
    for (int h = 0; h < 8; ++h)
        #pragma unroll
        for (int dt = 0; dt < 2; ++dt)
            #pragma unroll
            for (int r = 0; r < 4; ++r) {
                const int n = n0 + quad * 4 + r;
                const int d = h * 64 + (ms * 2 + dt) * 16 + lane16;
                A[(size_t)(b * N_ + n) * D_ + d] = f2bf(aacc[h][dt][r]);
            }
}

// ---------------------------------------------------------------------------
extern "C" void kernel_launch(void* const* d_in, const int* in_sizes, int n_in,
                              void* d_out, int out_size, void* d_ws, size_t ws_size,
                              hipStream_t stream)
{
    const float* Q  = (const float*)d_in[0];
    const float* K  = (const float*)d_in[1];
    const float* V  = (const float*)d_in[2];
    const float* Wq = (const float*)d_in[3];
    const float* bq = (const float*)d_in[4];
    const float* Wo = (const float*)d_in[5];
    const float* bo = (const float*)d_in[6];
    float* out = (float*)d_out;
    u16*   ws  = (u16*)d_ws;

    const size_t NBD = (size_t)B_ * N_ * D_;   // 4,194,304

    const size_t need6 = (6 * NBD + 2 * (size_t)D_ * D_) * sizeof(u16); // 51.4 MB

    if (ws_size >= need6) {
        // Path A: bf16-ify inputs once; proj1 all-gload pipelined.
        u16* S0 = ws;
        u16* S1 = ws + NBD;
        u16* S3 = ws + 3 * NBD;
        u16* Wb = ws + 6 * NBD;            // [Wqb | Wob]

        cvt4<<<dim3((unsigned)(NBD / 2048), 4), dim3(256), 0, stream>>>(
            Q, K, V, Wq, Wo, S0, Wb);

        proj1g<<<dim3(768), dim3(256), 0, stream>>>(S0, Wb, bq, S3);

        attn_mfma10<<<dim3(256), dim3(512), 0, stream>>>(
            S3, S3 + NBD, S3 + 2 * NBD, S0);   // partials -> S0, S1

        proj2p<<<dim3(512), dim3(256), 0, stream>>>(
            S0, S1, Wb + (size_t)D_ * D_, bo, out);
    } else {
        // Path B (43.0 MB): fp32-X reg-prefetch staging in proj1.
        u16* Qp  = ws;
        u16* Kp  = ws + NBD;
        u16* Vpt = ws + 2 * NBD;
        u16* Pa  = ws + 3 * NBD;
        u16* Pb  = ws + 4 * NBD;
        u16* Wb  = ws + 5 * NBD;

        wconv<<<dim3(128, 2), dim3(256), 0, stream>>>(Wq, Wo, Wb);

        proj1f<<<dim3(768), dim3(256), 0, stream>>>(Q, K, V, Wb, bq, Qp);

        attn_mfma10<<<dim3(256), dim3(512), 0, stream>>>(Qp, Kp, Vpt, Pa);

        proj2p<<<dim3(512), dim3(256), 0, stream>>>(
            Pa, Pb, Wb + (size_t)D_ * D_, bo, out);
    }
}